// Round 10
// baseline (212.215 us; speedup 1.0000x reference)
//
#include <hip/hip_runtime.h>

// MLP depends only on X[b] (1000 distinct values) -> params table, gathered
// by the scan. R10: scan restructured — phase A's 200-step exact chain
// writes every pre-step latent directly into the 32x200 LDS tile (chains
// spread over all 4 waves); corrects are a stateless fma of latent, so the
// old re-emission phase collapses into a parallel float4 sweep with
// contiguous nontemporal stores (R5 lesson: strided lane stores -> 4.85x
// write amplification). Outputs bit-identical to R9. Aux chain = R6/R9's
// proven prep + MFMA mlp x2 + params (R7 grid.sync ~60us/barrier and R8
// block-local VALU MLP both rejected on counters).

typedef unsigned int uint;
typedef unsigned char uchar;
typedef unsigned short ushort_t;
typedef __attribute__((ext_vector_type(8))) short short8;
typedef __attribute__((ext_vector_type(4))) float f32x4;
typedef __attribute__((ext_vector_type(2))) uint uint2v;

#define SS 1000
#define HH 512
#define TT 200
#define BB_ 65536
#define PP 5

#define OFF_EMB   0
#define OFF_B1    512000
#define OFF_B2    512512
#define OFF_WOUT  513024
#define OFF_BOUT  515584
#define CONV_TOT  515589

__device__ __forceinline__ float b2f(ushort_t u) {
    return __uint_as_float(((uint)u) << 16);
}
__device__ __forceinline__ ushort_t f2b(float f) {
    uint u = __float_as_uint(f);
    uint r = u + 0x7FFFu + ((u >> 16) & 1u);   // RNE
    return (ushort_t)(r >> 16);
}
// Per-wave dtype detect (R2-R9: dataset is f32; keep both paths).
__device__ __forceinline__ int detect_bf16(const uint* __restrict__ embed_raw,
                                           int tid) {
    uint w = embed_raw[tid & 63];
    uint e = (w >> 7) & 0xFFu;
    bool pl = (e >= 117u && e <= 130u);
    return __popcll(__ballot(pl)) >= 32 ? 1 : 0;
}
__device__ __forceinline__ ushort_t ld_bf16(const void* src, int idx, int fb) {
    return fb ? ((const ushort_t*)src)[idx] : f2b(((const float*)src)[idx]);
}

// The one true scan step (same fp ops/order everywhere).
__device__ __forceinline__ float bkt_step(float latent, bool yt,
                                          float oms, float omg, float A1,
                                          float A0, float g, float s,
                                          float oml, float l) {
    float num1    = latent * oms;
    float correct = fmaf(latent, A1, g);
    float lats    = latent * s;
    float num = yt ? num1 : lats;
    float den = yt ? correct : fmaf(latent, A0, omg);
    float kt  = num * __builtin_amdgcn_rcpf(den);
    float nxt = fmaf(kt, oml, l);
    return fminf(fmaxf(nxt, 1e-6f), 1.f - 1e-6f);
}

// ------------------------------------------------------------------- prep
// [0,504): vectorized conv copy (4 elems/thread; all section boundaries are
// multiples of 4 so a group never crosses sources). [504,1016): 32x32
// transpose tiles of W1/W2 (read raw, emit bf16 WT).
__global__ __launch_bounds__(256) void prep_kernel(
    const void* __restrict__ embed, const void* __restrict__ W1,
    const void* __restrict__ b1,    const void* __restrict__ W2,
    const void* __restrict__ b2,    const void* __restrict__ Wout,
    const void* __restrict__ bout,
    ushort_t* __restrict__ conv, ushort_t* __restrict__ WT1,
    ushort_t* __restrict__ WT2)
{
    int tid = threadIdx.x;
    int fb = detect_bf16((const uint*)embed, tid);
    int bx = blockIdx.x;
    if (bx < 504) {
        int i = (bx * 256 + tid) * 4;
        if (i < CONV_TOT) {
            const void* src; int off;
            if      (i < OFF_B1)   { src = embed; off = i; }
            else if (i < OFF_B2)   { src = b1;    off = i - OFF_B1; }
            else if (i < OFF_WOUT) { src = b2;    off = i - OFF_B2; }
            else if (i < OFF_BOUT) { src = Wout;  off = i - OFF_WOUT; }
            else                   { src = bout;  off = i - OFF_BOUT; }
            if (i + 3 < CONV_TOT) {
                ushort_t o0, o1, o2, o3;
                if (fb) {
                    ushort4 v = *(const ushort4*)((const ushort_t*)src + off);
                    o0 = v.x; o1 = v.y; o2 = v.z; o3 = v.w;
                } else {
                    float4 v = *(const float4*)((const float*)src + off);
                    o0 = f2b(v.x); o1 = f2b(v.y); o2 = f2b(v.z); o3 = f2b(v.w);
                }
                ushort4 o; o.x = o0; o.y = o1; o.z = o2; o.w = o3;
                *(ushort4*)(conv + i) = o;
            } else {
                for (int k = 0; i + k < CONV_TOT; k++)
                    conv[i + k] = ld_bf16(src, off + k, fb);
            }
        }
    } else {
        __shared__ ushort_t t[32][33];
        int bi = bx - 504;
        const void* W = bi < 256 ? W1 : W2;
        ushort_t* WT = bi < 256 ? WT1 : WT2;
        int ti = bi & 255;
        int k0 = (ti & 15) * 32, n0 = (ti >> 4) * 32;
        int tx = tid & 31, ty = tid >> 5;
        #pragma unroll
        for (int i = ty; i < 32; i += 8)
            t[i][tx] = ld_bf16(W, (k0 + i) * HH + n0 + tx, fb);
        __syncthreads();
        #pragma unroll
        for (int i = ty; i < 32; i += 8)
            WT[(n0 + i) * HH + k0 + tx] = t[tx][i];
    }
}

// -------------------------------------------------------------- MLP layer
// Wave computes a 16x16 MFMA tile; grid (16,32)=512 blocks (2/CU).
__global__ __launch_bounds__(256) void mlp_layer(
    const ushort_t* __restrict__ A, const ushort_t* __restrict__ WT,
    const ushort_t* __restrict__ bias, ushort_t* __restrict__ H, int Mclamp)
{
    int tid = threadIdx.x;
    int lane = tid & 63;
    int wave = tid >> 6;
    int m_base = blockIdx.x * 64 + wave * 16;
    int n_base = blockIdx.y * 16;
    int lrow = lane & 15;
    int q = lane >> 4;
    int rowA = m_base + lrow; if (rowA > Mclamp) rowA = Mclamp;

    const short8* Ap = (const short8*)(A + (size_t)rowA * HH) + q;
    const short8* Bp = (const short8*)(WT + (size_t)(n_base + lrow) * HH) + q;

    f32x4 acc = {0.f, 0.f, 0.f, 0.f};
    #pragma unroll 8
    for (int kk = 0; kk < 16; kk++) {
        short8 a = Ap[kk * 4];
        short8 b = Bp[kk * 4];
        acc = __builtin_amdgcn_mfma_f32_16x16x32_bf16(a, b, acc, 0, 0, 0);
    }

    int orow = m_base + q * 4;                 // C/D: col=lane&15, row=q*4+reg
    int n = n_base + lrow;
    float bb = b2f(bias[n]);
    #pragma unroll
    for (int r = 0; r < 4; r++) {
        float v = acc[r] + bb;
        H[(size_t)(orow + r) * HH + n] = f2b(fmaxf(v, 0.f));
    }
}

// ---------------------------------------------------------------- params
__global__ __launch_bounds__(256) void params_kernel(
    const ushort_t* __restrict__ h2, const ushort_t* __restrict__ conv,
    float* __restrict__ table)
{
    int wid = blockIdx.x * 4 + (threadIdx.x >> 6);
    int lane = threadIdx.x & 63;
    if (wid >= SS * PP) return;
    int row = wid / PP, p = wid - row * PP;
    const ushort_t* Wout = conv + OFF_WOUT;
    const ushort_t* bout = conv + OFF_BOUT;
    const short8* hr = (const short8*)(h2 + (size_t)row * HH);
    short8 h = hr[lane];
    float acc = 0.f;
    #pragma unroll
    for (int j = 0; j < 8; j++) {
        int k = lane * 8 + j;
        acc += b2f((ushort_t)h[j]) * b2f(Wout[k * PP + p]);
    }
    #pragma unroll
    for (int m = 32; m; m >>= 1) acc += __shfl_xor(acc, m);
    if (lane == 0) {
        float x = acc + b2f(bout[p]);
        float sg = 1.f / (1.f + expf(-x));
        sg = fminf(fmaxf(sg, 1e-6f), 1.f - 1e-6f);
        table[(size_t)row * 8 + p] = sg;
    }
}

// ---------------------------------------------------------------- scan
// One block = 32 rows. Phase 0: y -> LDS nibbles (coalesced int4).
// Phase A: 32 exact 200-step chains spread over 4 waves (lanes 0-7 each),
// writing every pre-step latent into the 32x200 LDS tile (ds_writes don't
// extend the dep chain); per-row A1,g to LDS; params output written here.
// Sweep: 256 threads, float4 LDS reads -> nontemporal latent stores + 4 FMAs
// -> nontemporal correct stores. Only 2 barriers, no re-emission chains.
__global__ __launch_bounds__(256) void scan_kernel(
    const int* __restrict__ X, const int* __restrict__ y,
    const float* __restrict__ table, const uint* __restrict__ embed_raw,
    void* __restrict__ out)
{
    __shared__ __align__(16) float stg[32 * 200];      // 25600 B
    __shared__ uchar ybit[32 * 50];                    // 1600 B
    __shared__ float pA1[32], pG[32];
    int tid = threadIdx.x;
    int rbase = blockIdx.x * 32;
    int fb = detect_bf16(embed_raw, tid);

    // phase 0
    for (int idx = tid; idx < 1600; idx += 256) {
        int r = idx / 50, k = idx - r * 50;
        int4 v = *(const int4*)(y + (size_t)(rbase + r) * TT + k * 4);
        ybit[r * 50 + k] = (uchar)((uint)(v.x == 1) | ((uint)(v.y == 1) << 1) |
                                   ((uint)(v.z == 1) << 2) | ((uint)(v.w == 1) << 3));
    }
    __syncthreads();

    // phase A
    int lane = tid & 63, wv = tid >> 6;
    if (lane < 8) {
        int r = wv * 8 + lane;                 // 0..31
        int rg = rbase + r;
        int xi = X[rg]; xi = xi < 0 ? 0 : (xi >= SS ? SS - 1 : xi);
        float l      = table[xi * 8 + 0];
        float p1     = table[xi * 8 + 1];
        float g      = table[xi * 8 + 2];
        float s      = table[xi * 8 + 3];
        float L0     = table[xi * 8 + 4];
        float oms = 1.f - s, omg = 1.f - g, oml = 1.f - l;
        float A1 = 1.f - s - g, A0 = s + g - 1.f;
        pA1[r] = A1; pG[r] = g;

        if (fb) {
            ushort_t* pp = (ushort_t*)out + 2ull * BB_ * TT + (size_t)rg * 5;
            pp[0] = f2b(l); pp[1] = f2b(p1); pp[2] = f2b(g);
            pp[3] = f2b(s); pp[4] = f2b(L0);
        } else {
            float* pp = (float*)out + 2ull * BB_ * TT + (size_t)rg * 5;
            pp[0] = l; pp[1] = p1; pp[2] = g; pp[3] = s; pp[4] = L0;
        }

        float latent = L0;
        const uchar* yb = &ybit[r * 50];
        float* srow = &stg[r * 200];
        for (int k = 0; k < 50; k++) {
            uint nib = yb[k];
            #pragma unroll
            for (int i = 0; i < 4; i++) {
                srow[k * 4 + i] = latent;
                latent = bkt_step(latent, (nib >> i) & 1u,
                                  oms, omg, A1, A0, g, s, oml, l);
            }
        }
    }
    __syncthreads();

    // sweep: corrects = fma(latent, A1_row, g_row); both stores contiguous
    const f32x4* src = (const f32x4*)stg;
    if (!fb) {
        f32x4* dc = (f32x4*)((float*)out + (size_t)rbase * TT);
        f32x4* dl = (f32x4*)((float*)out + (size_t)BB_ * TT + (size_t)rbase * TT);
        for (int idx = tid; idx < 1600; idx += 256) {
            int r = idx / 50;
            f32x4 v = src[idx];
            float A1 = pA1[r], g = pG[r];
            f32x4 c;
            c[0] = fmaf(v[0], A1, g); c[1] = fmaf(v[1], A1, g);
            c[2] = fmaf(v[2], A1, g); c[3] = fmaf(v[3], A1, g);
            __builtin_nontemporal_store(v, dl + idx);
            __builtin_nontemporal_store(c, dc + idx);
        }
    } else {
        uint2v* dc = (uint2v*)((ushort_t*)out + (size_t)rbase * TT);
        uint2v* dl = (uint2v*)((ushort_t*)out + (size_t)BB_ * TT + (size_t)rbase * TT);
        for (int idx = tid; idx < 1600; idx += 256) {
            int r = idx / 50;
            f32x4 v = src[idx];
            float A1 = pA1[r], g = pG[r];
            uint2v lv, cv;
            lv[0] = (uint)f2b(v[0]) | ((uint)f2b(v[1]) << 16);
            lv[1] = (uint)f2b(v[2]) | ((uint)f2b(v[3]) << 16);
            cv[0] = (uint)f2b(fmaf(v[0], A1, g)) | ((uint)f2b(fmaf(v[1], A1, g)) << 16);
            cv[1] = (uint)f2b(fmaf(v[2], A1, g)) | ((uint)f2b(fmaf(v[3], A1, g)) << 16);
            __builtin_nontemporal_store(lv, dl + idx);
            __builtin_nontemporal_store(cv, dc + idx);
        }
    }
}

// ---------------------------------------------------------------- launch
extern "C" void kernel_launch(void* const* d_in, const int* in_sizes, int n_in,
                              void* d_out, int out_size, void* d_ws, size_t ws_size,
                              hipStream_t stream) {
    const int* X = (const int*)d_in[0];
    const int* y = (const int*)d_in[1];

    char* ws = (char*)d_ws;
    ushort_t* conv  = (ushort_t*)(ws);                 // ~1.03 MB used
    ushort_t* WT1   = (ushort_t*)(ws + 1048576);       // 512 KB
    ushort_t* WT2   = (ushort_t*)(ws + 1572864);       // 512 KB
    ushort_t* h1    = (ushort_t*)(ws + 2097152);       // 1 MB
    ushort_t* h2    = (ushort_t*)(ws + 3145728);       // 1 MB
    float*    table = (float*)(ws + 4194304);          // 32 KB

    prep_kernel<<<dim3(1016, 1, 1), 256, 0, stream>>>(
        d_in[2], d_in[3], d_in[4], d_in[5], d_in[6], d_in[7], d_in[8],
        conv, WT1, WT2);
    mlp_layer<<<dim3(16, 32, 1), 256, 0, stream>>>(conv + OFF_EMB, WT1, conv + OFF_B1, h1, SS - 1);
    mlp_layer<<<dim3(16, 32, 1), 256, 0, stream>>>(h1, WT2, conv + OFF_B2, h2, 1023);
    params_kernel<<<dim3(1250, 1, 1), 256, 0, stream>>>(h2, conv, table);
    scan_kernel<<<dim3(2048, 1, 1), 256, 0, stream>>>(
        X, y, table, (const uint*)d_in[2], (void*)d_out);
}